// Round 8
// baseline (38.667 us; speedup 1.0000x reference)
//
#include <hip/hip_runtime.h>
#include <hip/hip_bf16.h>
#include <hip/hip_fp16.h>

typedef _Float16 f16x8 __attribute__((ext_vector_type(8)));
typedef float f32x4 __attribute__((ext_vector_type(4)));

#define N_PTS 32768
#define NCHUNK 65       // 64 h-chunks + 1 bias chunk (h == 1)
#define ROWS_BLK 128    // rows per block (4 waves x 32 rows)
#define H_STRIDE 72     // f16; 144 B rows: 16B-aligned b128 writes, reads 2-way max

// ---- prep: repack W2 (fp32 [4096][64]) + b2 (fp32 [4096]) into f16 MFMA
// fragment layout (unchanged from R6, proven correct).
__global__ __launch_bounds__(256) void prep_kernel(
    const float* __restrict__ W2, const float* __restrict__ b2,
    _Float16* __restrict__ wsB) {
  __shared__ _Float16 w_lds[64][H_STRIDE];
  const int c   = blockIdx.x;
  const int tid = threadIdx.x;
  {
    const float* src = (c < 64) ? (W2 + c * 4096 + tid * 16) : (b2 + tid * 16);
    int kl = tid >> 2, o = (tid & 3) * 16;
    f16x8 v0, v1;
    #pragma unroll
    for (int j = 0; j < 8; ++j) {
      v0[j] = (_Float16)src[j];
      v1[j] = (_Float16)src[8 + j];
    }
    *(f16x8*)(&w_lds[kl][o])     = v0;
    *(f16x8*)(&w_lds[kl][o + 8]) = v1;
  }
  __syncthreads();
  #pragma unroll
  for (int u = 0; u < 2; ++u) {
    int t = tid + u * 256;           // dest chunk index within c: 0..511
    int q = t >> 6, lane = t & 63;
    int klbase = (q >> 2) * 32 + ((lane >> 4) & 3) * 8;
    int o      = (q & 3) * 16 + (lane & 15);
    f16x8 v;
    #pragma unroll
    for (int j = 0; j < 8; ++j) v[j] = w_lds[klbase + j][o];
    *(f16x8*)(wsB + c * 4096 + t * 8) = v;
  }
}

// ---- main fused kernel: canonical LDS-staged GEMM ----
// 256 blocks x 256 threads (4 waves). Block owns 128 rows; each wave 32 rows
// (2 m-tiles), acc 2x4 f32x4 is FINAL (no K-split, no reduce). K-step = chunk
// pair (16 KB contiguous in wsB), double-buffered in LDS via reg-staging:
// issue loads early, ds_write late (T14), one barrier per step. Chunk-pair
// order rotated per block to de-hotspot L2.
__global__ __launch_bounds__(256) void main_kernel(
    const float* __restrict__ x, const float* __restrict__ gridp,
    const float* __restrict__ W1, const float* __restrict__ b1,
    const _Float16* __restrict__ wsB, float* __restrict__ out) {

  __shared__ _Float16 bbuf[2][8192];             // 2 x 16 KB staged B pair
  __shared__ _Float16 biasb[4096];               // 8 KB bias-chunk frags
  __shared__ _Float16 h_lds[ROWS_BLK][H_STRIDE]; // 18432 B ; total 59392 B

  const int tid  = threadIdx.x;
  const int lane = tid & 63;
  const int wave = tid >> 6;
  const int rowblk = blockIdx.x * ROWS_BLK;
  const int rot = blockIdx.x & 31;
  const int mrow = lane & 15;        // A row within 16-tile / D col
  const int kgrp = lane >> 4;        // 0..3

  const char* wsb = (const char*)wsB;
  auto pidx = [&](int s) { return (s + rot) & 31; };   // pair index, rotated

  // -- prologue: issue staging loads for pair(0) + bias chunk (6 dwordx4) --
  f32x4 st[4], sb[2];
  {
    int p0 = pidx(0);
    #pragma unroll
    for (int i = 0; i < 4; ++i)
      st[i] = *(const f32x4*)(wsb + p0 * 16384 + (wave + 4 * i) * 1024 + lane * 16);
    #pragma unroll
    for (int i = 0; i < 2; ++i)
      sb[i] = *(const f32x4*)(wsb + 64 * 8192 + (wave + 4 * i) * 1024 + lane * 16);
  }

  // -- x fragment loads (fp32, 16x 16B) --
  f32x4 xr[2][2][2];
  #pragma unroll
  for (int m = 0; m < 2; ++m)
    #pragma unroll
    for (int s = 0; s < 2; ++s) {
      const float* xp = x + (rowblk + wave * 32 + m * 16 + mrow) * 64 + s * 32 + kgrp * 8;
      xr[m][s][0] = *(const f32x4*)(xp);
      xr[m][s][1] = *(const f32x4*)(xp + 4);
    }

  // -- h phase: row = tid>>1, half = tid&1, 32 k per thread (under load shadow)
  {
    int row = tid >> 1, half = tid & 1;
    int r = rowblk + row;
    float g0 = gridp[r * 3 + 0], g1 = gridp[r * 3 + 1], g2 = gridp[r * 3 + 2];
    #pragma unroll
    for (int kb = 0; kb < 32; kb += 8) {
      f16x8 hv;
      #pragma unroll
      for (int q = 0; q < 8; ++q) {
        int k = half * 32 + kb + q;
        float v = g0 * W1[k] + g1 * W1[64 + k] + g2 * W1[128 + k] + b1[k];
        hv[q] = (_Float16)(0.5f * v * (1.0f + erff(v * 0.7071067811865476f)));
      }
      *(f16x8*)(&h_lds[row][half * 32 + kb]) = hv;
    }
  }

  // -- convert x to f16 fragments --
  f16x8 xf[2][2];
  #pragma unroll
  for (int m = 0; m < 2; ++m)
    #pragma unroll
    for (int s = 0; s < 2; ++s) {
      f16x8 v;
      #pragma unroll
      for (int j = 0; j < 4; ++j) {
        v[j]     = (_Float16)xr[m][s][0][j];
        v[4 + j] = (_Float16)xr[m][s][1][j];
      }
      xf[m][s] = v;
    }

  // -- write staged pair(0) + bias into LDS, then one barrier --
  #pragma unroll
  for (int i = 0; i < 4; ++i)
    *(f32x4*)((char*)&bbuf[0][0] + (wave + 4 * i) * 1024 + lane * 16) = st[i];
  #pragma unroll
  for (int i = 0; i < 2; ++i)
    *(f32x4*)((char*)&biasb[0] + (wave + 4 * i) * 1024 + lane * 16) = sb[i];
  __syncthreads();

  f32x4 acc[2][4];
  #pragma unroll
  for (int m = 0; m < 2; ++m)
    #pragma unroll
    for (int n = 0; n < 4; ++n)
      acc[m][n] = (f32x4){0.f, 0.f, 0.f, 0.f};

  auto FRAGS = [&](const _Float16* buf, int ch, f16x8* b) {
    #pragma unroll
    for (int q = 0; q < 8; ++q)
      b[q] = *(const f16x8*)(buf + ch * 4096 + q * 512 + lane * 8);
  };
  auto COMPUTE = [&](const f16x8* b, int c) {
    #pragma unroll
    for (int m = 0; m < 2; ++m) {
      _Float16 hh = h_lds[wave * 32 + m * 16 + mrow][c];
      f16x8 hs = {hh, hh, hh, hh, hh, hh, hh, hh};
      f16x8 a0 = xf[m][0] * hs;
      f16x8 a1 = xf[m][1] * hs;
      #pragma unroll
      for (int n = 0; n < 4; ++n) {
        acc[m][n] = __builtin_amdgcn_mfma_f32_16x16x32_f16(a0, b[n],     acc[m][n], 0, 0, 0);
        acc[m][n] = __builtin_amdgcn_mfma_f32_16x16x32_f16(a1, b[4 + n], acc[m][n], 0, 0, 0);
      }
    }
  };

  // -- main loop: 32 steps (2 per iteration, static dbuf parity) --
  for (int t = 0; t < 16; ++t) {
    {   // step 2t: read bbuf[0] (pair pidx(2t)), stage pair pidx(2t+1) -> bbuf[1]
      int pn = pidx(2 * t + 1);
      f32x4 stg[4];
      #pragma unroll
      for (int i = 0; i < 4; ++i)
        stg[i] = *(const f32x4*)(wsb + pn * 16384 + (wave + 4 * i) * 1024 + lane * 16);
      int c0 = 2 * pidx(2 * t);
      f16x8 b0[8], b1[8];
      FRAGS(bbuf[0], 0, b0);
      FRAGS(bbuf[0], 1, b1);
      COMPUTE(b0, c0);
      COMPUTE(b1, c0 + 1);
      #pragma unroll
      for (int i = 0; i < 4; ++i)
        *(f32x4*)((char*)&bbuf[1][0] + (wave + 4 * i) * 1024 + lane * 16) = stg[i];
      __syncthreads();
    }
    {   // step 2t+1: read bbuf[1], stage pair pidx(2t+2) -> bbuf[0] (skip last)
      int c0 = 2 * pidx(2 * t + 1);
      f32x4 stg[4];
      if (t < 15) {
        int pn = pidx(2 * t + 2);
        #pragma unroll
        for (int i = 0; i < 4; ++i)
          stg[i] = *(const f32x4*)(wsb + pn * 16384 + (wave + 4 * i) * 1024 + lane * 16);
      }
      f16x8 b0[8], b1[8];
      FRAGS(bbuf[1], 0, b0);
      FRAGS(bbuf[1], 1, b1);
      COMPUTE(b0, c0);
      COMPUTE(b1, c0 + 1);
      if (t < 15) {
        #pragma unroll
        for (int i = 0; i < 4; ++i)
          *(f32x4*)((char*)&bbuf[0][0] + (wave + 4 * i) * 1024 + lane * 16) = stg[i];
        __syncthreads();
      }
    }
  }

  // -- bias chunk (h == 1): A-frag = xf directly --
  {
    f16x8 bb[8];
    FRAGS(biasb, 0, bb);
    #pragma unroll
    for (int m = 0; m < 2; ++m)
      #pragma unroll
      for (int n = 0; n < 4; ++n) {
        acc[m][n] = __builtin_amdgcn_mfma_f32_16x16x32_f16(xf[m][0], bb[n],     acc[m][n], 0, 0, 0);
        acc[m][n] = __builtin_amdgcn_mfma_f32_16x16x32_f16(xf[m][1], bb[4 + n], acc[m][n], 0, 0, 0);
      }
  }

  // -- epilogue: direct store (acc is final; no reduce) --
  #pragma unroll
  for (int m = 0; m < 2; ++m)
    #pragma unroll
    for (int n = 0; n < 4; ++n) {
      int row = rowblk + wave * 32 + m * 16 + kgrp * 4;
      #pragma unroll
      for (int r = 0; r < 4; ++r)
        out[(row + r) * 64 + n * 16 + mrow] = acc[m][n][r];
    }
}

extern "C" void kernel_launch(void* const* d_in, const int* in_sizes, int n_in,
                              void* d_out, int out_size, void* d_ws, size_t ws_size,
                              hipStream_t stream) {
  const float* x    = (const float*)d_in[0];
  const float* grid = (const float*)d_in[1];
  const float* W1   = (const float*)d_in[2];
  const float* b1   = (const float*)d_in[3];
  const float* W2   = (const float*)d_in[4];
  const float* b2   = (const float*)d_in[5];
  float* out = (float*)d_out;
  _Float16* wsB = (_Float16*)d_ws;   // needs 65*4096*2 = 532480 bytes

  hipLaunchKernelGGL(prep_kernel, dim3(NCHUNK), dim3(256), 0, stream,
                     W2, b2, wsB);
  hipLaunchKernelGGL(main_kernel, dim3(N_PTS / ROWS_BLK), dim3(256), 0, stream,
                     x, grid, W1, b1, wsB, out);
}